// Round 18
// baseline (236.203 us; speedup 1.0000x reference)
//
#include <hip/hip_runtime.h>
#include <hip/hip_bf16.h>
#include <stdint.h>

// Problem constants
#define BB 64      // batch
#define JJ 2048    // input capsules
#define DI 16      // input dim
#define CC 32      // output capsules
#define OO 32      // output dim
#define CO 1024    // CC*OO
#define TJ 16      // j per block
#define NJT 128    // JJ/TJ

static const size_t W2_BYTES = (size_t)CC * JJ * OO * DI * 2;  // 64 MB
static const size_t X3_BYTES = (size_t)BB * JJ * DI * 2;       // 4 MB

typedef _Float16 f16x4 __attribute__((ext_vector_type(4)));
typedef float    f32x4 __attribute__((ext_vector_type(4)));
typedef unsigned short ushort_t;

// __has_builtin on amdgcn builtins is false in the host pass (R7 lesson).
#if defined(__HIP_DEVICE_COMPILE__)
# if __has_builtin(__builtin_amdgcn_mfma_f32_16x16x16f16)
#  define MFMA16(a, b, c) __builtin_amdgcn_mfma_f32_16x16x16f16((a), (b), (c), 0, 0, 0)
# else
#  define MFMA16(a, b, c) __builtin_amdgcn_mfma_f32_16x16x16_f16((a), (b), (c), 0, 0, 0)
# endif
# define SCHED_FENCE() __builtin_amdgcn_sched_barrier(0)
#else
# define MFMA16(a, b, c) (c)
# define SCHED_FENCE()
#endif

union Pack2 { unsigned u; _Float16 h[2]; };

__device__ __forceinline__ ushort_t f2bf(float f) {   // RNE f32 -> bf16
  unsigned u = __float_as_uint(f);
  u += 0x7FFFu + ((u >> 16) & 1u);
  return (ushort_t)(u >> 16);
}
__device__ __forceinline__ float bf2f(ushort_t b) {
  return __uint_as_float(((unsigned)b) << 16);
}

// W [c][j][o][i] f32 -> W2 f16 in A-fragment order (A = W, rows = co, k = i):
// entry s = ct*64 + l of slab j holds W[co = ct*16 + (l&15)][i = 4*(l>>4)+e].
__global__ __launch_bounds__(256) void prep_w(const float* __restrict__ W,
                                              uint2* __restrict__ W2) {
  const int j = blockIdx.x;    // 2048
  const int tt = threadIdx.x;  // 256
#pragma unroll
  for (int r = 0; r < 16; ++r) {
    const int s = r * 256 + tt;           // 0..4095 = ct*64 + l
    const int ct = s >> 6, l = s & 63;
    const int co = ct * 16 + (l & 15);
    const int c = co >> 5, o = co & 31;
    const float4 src = ((const float4*)W)[(((size_t)c * JJ + j) * OO + o) * 4 + (l >> 4)];
    Pack2 a, b;
    a.h[0] = (_Float16)src.x; a.h[1] = (_Float16)src.y;
    b.h[0] = (_Float16)src.z; b.h[1] = (_Float16)src.w;
    W2[(size_t)j * 4096 + s] = make_uint2(a.u, b.u);
  }
}

// x [b][j][i] f32 -> X3 f16 in B-fragment order (B = x, cols = b, k = i).
__global__ __launch_bounds__(256) void prep_x(const float* __restrict__ X,
                                              uint2* __restrict__ X3) {
  const unsigned T = blockIdx.x * 256 + threadIdx.x;   // 524288
  const int l = T & 63, bt = (T >> 6) & 1, j = (T >> 7) & 2047, bq = (int)(T >> 18);
  const int b = bq * 32 + bt * 16 + (l & 15);
  const float4 src = ((const float4*)X)[((size_t)b * JJ + j) * 4 + (l >> 4)];
  Pack2 a, bb;
  a.h[0] = (_Float16)src.x; a.h[1] = (_Float16)src.y;
  bb.h[0] = (_Float16)src.z; bb.h[1] = (_Float16)src.w;
  X3[T] = make_uint2(a.u, bb.u);
}

// R18: R16's pair-processed MFMA route + R17's fixes (VGPR pinned via
// __launch_bounds__(1024,4); bf16 partial). Grid NJT*2 = 256 blocks of 1024
// (16 waves). Per iteration p: both j = 2p, 2p+1 share one barrier round-set
// (3 barriers per 2 j). 4 W slabs as two pair-buffers; stage pair p+2 after
// the logit barrier (all wbuf ds_reads drained by its lgkmcnt(0)). uh packed
// to f16 between logit and accumulate to fit the 128-VGPR budget.
template<bool HAVE_V>
__global__ __launch_bounds__(1024, 4) void route_pair(
    const uint4* __restrict__ X3, const uint4* __restrict__ W2,
    const float* __restrict__ vsum, ushort_t* __restrict__ partial)
{
  __shared__ uint4 wbuf[4][2048];    // 4 x 32KB W slabs
  __shared__ uint4 xbuf[1024];       // 16KB x B-frags
  __shared__ float lbuf[2][32 * 33]; // [pair-member q][32 b-rows x 32 c (+1 pad)]

  const int jt   = blockIdx.x & (NJT - 1);
  const int bq   = blockIdx.x >> 7;
  const int tid  = threadIdx.x;
  const int w    = tid >> 6;
  const int lane = tid & 63;
  const int g    = lane >> 4;
  const int t    = lane & 15;

  // vsum packed f16 pairs (16 VGPR): [cc][bt][hh][rp]
  unsigned vsh[2][2][2][2];
  if (HAVE_V) {
#pragma unroll
    for (int cc = 0; cc < 2; ++cc)
#pragma unroll
      for (int bt = 0; bt < 2; ++bt)
#pragma unroll
        for (int hh = 0; hh < 2; ++hh)
#pragma unroll
          for (int rp = 0; rp < 2; ++rp) {
            const float* vp = vsum + (size_t)(bq * 32 + bt * 16 + t) * CO
                            + (2 * w + cc) * OO + hh * 16 + 4 * g + 2 * rp;
            Pack2 p; p.h[0] = (_Float16)vp[0]; p.h[1] = (_Float16)vp[1];
            vsh[cc][bt][hh][rp] = p.u;
          }
  }

  const uint4* wsrc = W2 + (size_t)jt * TJ * 2048;   // 16B units, 2048/j

#define STAGEW(slot, slab) do {                                                   \
    const uint4* sp_ = wsrc + (size_t)(slab) * 2048 + tid;                        \
    uint4* dp_ = &wbuf[slot][tid];                                                \
    _Pragma("unroll")                                                             \
    for (int r_ = 0; r_ < 2; ++r_)                                                \
      __builtin_amdgcn_global_load_lds(                                           \
          (const __attribute__((address_space(1))) void*)(sp_ + r_ * 1024),       \
          (__attribute__((address_space(3))) void*)(dp_ + r_ * 1024), 16, 0, 0);  \
  } while (0)

  // prologue: x (1 instr/thread) + pair 0 -> slots 0,1; pair 1 -> slots 2,3
  {
    const uint4* xs = X3 + ((size_t)bq * JJ + jt * TJ) * 64 + tid;
    __builtin_amdgcn_global_load_lds(
        (const __attribute__((address_space(1))) void*)xs,
        (__attribute__((address_space(3))) void*)&xbuf[tid], 16, 0, 0);
  }
  STAGEW(0, 0);
  STAGEW(1, 1);
  STAGEW(2, 2);
  STAGEW(3, 3);

  f32x4 acc[4][2];
#pragma unroll
  for (int k = 0; k < 4; ++k)
#pragma unroll
    for (int bt = 0; bt < 2; ++bt) acc[k][bt] = f32x4{0.f, 0.f, 0.f, 0.f};

  for (int p = 0; p < TJ / 2; ++p) {
    // pair p landed (pair p+1's 4 stage-instrs may stay in flight)
    if (p < TJ / 2 - 1) asm volatile("s_waitcnt vmcnt(4) lgkmcnt(0)" ::: "memory");
    else                asm volatile("s_waitcnt vmcnt(0) lgkmcnt(0)" ::: "memory");
    SCHED_FENCE();
    __builtin_amdgcn_s_barrier();

    const int sbase = 2 * (p & 1);
    const uint2* xb2 = (const uint2*)xbuf;

    // ds reads + MFMA + (logits, f16-pack) for both pair members
    unsigned uhp[2][4][2][2];   // [q][k][bt][half] : uh packed f16 (32 VGPR)
#pragma unroll
    for (int q = 0; q < 2; ++q) {
      const int jj = 2 * p + q;
      const uint2* wb2 = (const uint2*)wbuf[sbase + q];

      f16x4 bf[2];
#pragma unroll
      for (int bt = 0; bt < 2; ++bt)
        bf[bt] = __builtin_bit_cast(f16x4, xb2[(jj * 2 + bt) * 64 + lane]);
      f16x4 af[4];
#pragma unroll
      for (int k = 0; k < 4; ++k)
        af[k] = __builtin_bit_cast(f16x4, wb2[(w * 4 + k) * 64 + lane]);

      if (!HAVE_V) {
#pragma unroll
        for (int k = 0; k < 4; ++k)
#pragma unroll
          for (int bt = 0; bt < 2; ++bt)
            acc[k][bt] = MFMA16(af[k], bf[bt], acc[k][bt]);
      } else {
        f32x4 uh[4][2];
#pragma unroll
        for (int k = 0; k < 4; ++k)
#pragma unroll
          for (int bt = 0; bt < 2; ++bt)
            uh[k][bt] = MFMA16(af[k], bf[bt], (f32x4{0.f, 0.f, 0.f, 0.f}));

        // logits: 8 in-lane fma per (cc,bt) + xor16/32
        float lp[2][2];
#pragma unroll
        for (int cc = 0; cc < 2; ++cc)
#pragma unroll
          for (int bt = 0; bt < 2; ++bt) {
            float s = 0.f;
#pragma unroll
            for (int hh = 0; hh < 2; ++hh)
#pragma unroll
              for (int rp = 0; rp < 2; ++rp) {
                Pack2 pk; pk.u = vsh[cc][bt][hh][rp];
                s = fmaf(uh[2 * cc + hh][bt][2 * rp],     (float)pk.h[0], s);
                s = fmaf(uh[2 * cc + hh][bt][2 * rp + 1], (float)pk.h[1], s);
              }
            s += __shfl_xor(s, 16);
            s += __shfl_xor(s, 32);
            lp[cc][bt] = s;
          }
        {
          const float hi = (g & 1) ? lp[1][1] : lp[1][0];
          const float lo = (g & 1) ? lp[0][1] : lp[0][0];
          const float val = (g >> 1) ? hi : lo;
          lbuf[q][((g & 1) * 16 + t) * 33 + 2 * w + (g >> 1)] = val;
        }
        // pack uh -> f16 (frees the f32 set)
#pragma unroll
        for (int k = 0; k < 4; ++k)
#pragma unroll
          for (int bt = 0; bt < 2; ++bt) {
            Pack2 p0, p1;
            p0.h[0] = (_Float16)uh[k][bt][0]; p0.h[1] = (_Float16)uh[k][bt][1];
            p1.h[0] = (_Float16)uh[k][bt][2]; p1.h[1] = (_Float16)uh[k][bt][3];
            uhp[q][k][bt][0] = p0.u; uhp[q][k][bt][1] = p1.u;
          }
      }
    }

    if (HAVE_V) {
      asm volatile("s_waitcnt lgkmcnt(0)" ::: "memory");
      SCHED_FENCE();
      __builtin_amdgcn_s_barrier();
      // all wbuf reads of pair p drained -> safe to overwrite its slots
      if (2 * p + 5 < TJ) { STAGEW(sbase, 2 * p + 4); STAGEW(sbase + 1, 2 * p + 5); }

      // softmax: both parities; wave w owns rows 2w, 2w+1 per parity
#pragma unroll
      for (int q = 0; q < 2; ++q) {
        const int row = 2 * w + (lane >> 5);
        const int cc2 = lane & 31;
        float e = __expf(lbuf[q][row * 33 + cc2]);
        float den = e;
        den += __shfl_xor(den, 1);  den += __shfl_xor(den, 2);
        den += __shfl_xor(den, 4);  den += __shfl_xor(den, 8);
        den += __shfl_xor(den, 16);
        lbuf[q][row * 33 + cc2] = e / den;
      }
      asm volatile("s_waitcnt lgkmcnt(0)" ::: "memory");
      SCHED_FENCE();
      __builtin_amdgcn_s_barrier();

      // coefs + accumulate (unpack uhp)
#pragma unroll
      for (int q = 0; q < 2; ++q) {
        float cf[2][2];
#pragma unroll
        for (int cc = 0; cc < 2; ++cc)
#pragma unroll
          for (int bt = 0; bt < 2; ++bt)
            cf[cc][bt] = lbuf[q][(bt * 16 + t) * 33 + 2 * w + cc];
#pragma unroll
        for (int k = 0; k < 4; ++k)
#pragma unroll
          for (int bt = 0; bt < 2; ++bt) {
            Pack2 p0, p1;
            p0.u = uhp[q][k][bt][0]; p1.u = uhp[q][k][bt][1];
            acc[k][bt][0] = fmaf(cf[k >> 1][bt], (float)p0.h[0], acc[k][bt][0]);
            acc[k][bt][1] = fmaf(cf[k >> 1][bt], (float)p0.h[1], acc[k][bt][1]);
            acc[k][bt][2] = fmaf(cf[k >> 1][bt], (float)p1.h[0], acc[k][bt][2]);
            acc[k][bt][3] = fmaf(cf[k >> 1][bt], (float)p1.h[1], acc[k][bt][3]);
          }
      }
    } else {
      // pass 0: drain ds reads, sync, then overwrite pair p's slots
      asm volatile("s_waitcnt lgkmcnt(0)" ::: "memory");
      SCHED_FENCE();
      __builtin_amdgcn_s_barrier();
      if (2 * p + 5 < TJ) { STAGEW(sbase, 2 * p + 4); STAGEW(sbase + 1, 2 * p + 5); }
    }
  }
#undef STAGEW

  // D layout: col = t -> b, rows 4g+r -> co; acc[k][bt] = 4 consecutive co
  // -> bf16 ushort4 store (8B), halves partial traffic.
  const float cs = HAVE_V ? 1.f : 0.03125f;
#pragma unroll
  for (int k = 0; k < 4; ++k)
#pragma unroll
    for (int bt = 0; bt < 2; ++bt) {
      const int b  = bq * 32 + bt * 16 + t;
      const int co = (4 * w + k) * 16 + 4 * g;
      ushort4 v;
      v.x = f2bf(acc[k][bt][0] * cs);
      v.y = f2bf(acc[k][bt][1] * cs);
      v.z = f2bf(acc[k][bt][2] * cs);
      v.w = f2bf(acc[k][bt][3] * cs);
      *(ushort4*)(partial + ((size_t)jt * BB + b) * CO + co) = v;
    }
}

// ---------------- f32 fallback route (proven R2/R4 path) ----------------
template<bool HAVE_V>
__global__ __launch_bounds__(256, 1) void route_f32(
    const float* __restrict__ X, const float* __restrict__ W,
    const float* __restrict__ vsum, float* __restrict__ partial)
{
  const int jt   = blockIdx.x & 63;
  const int bq   = blockIdx.x >> 6;
  const int tid  = threadIdx.x;
  const int wave = tid >> 6;
  const int lane = tid & 63;
  const int c    = lane & 31;
  const int o0   = (lane >> 5) << 4;
  const int b0   = bq * 16 + wave * 4;

  float acc[4][16];
#pragma unroll
  for (int bl = 0; bl < 4; ++bl)
#pragma unroll
    for (int ol = 0; ol < 16; ++ol) acc[bl][ol] = 0.f;

  const float* wbase = W + ((size_t)c * JJ * OO + (size_t)o0) * DI;

  for (int jj = 0; jj < 32; ++jj) {
    const int j = jt * 32 + jj;
    float xf[4][16];
#pragma unroll
    for (int bl = 0; bl < 4; ++bl) {
      const float4* xpt = (const float4*)(X + ((size_t)(b0 + bl) * JJ + j) * DI);
#pragma unroll
      for (int q = 0; q < 4; ++q) {
        float4 x4 = xpt[q];
        xf[bl][4*q+0] = x4.x; xf[bl][4*q+1] = x4.y;
        xf[bl][4*q+2] = x4.z; xf[bl][4*q+3] = x4.w;
      }
    }
    const float4* wp = (const float4*)(wbase + (size_t)j * OO * DI);
    float tv[4][16];
#pragma unroll
    for (int ol = 0; ol < 16; ++ol) {
      float wf[16];
#pragma unroll
      for (int q = 0; q < 4; ++q) {
        float4 w4 = wp[4*ol + q];
        wf[4*q+0] = w4.x; wf[4*q+1] = w4.y;
        wf[4*q+2] = w4.z; wf[4*q+3] = w4.w;
      }
#pragma unroll
      for (int bl = 0; bl < 4; ++bl) {
        float tt = 0.f;
#pragma unroll
        for (int i = 0; i < 16; ++i) tt = fmaf(wf[i], xf[bl][i], tt);
        if (!HAVE_V) acc[bl][ol] += tt;
        else         tv[bl][ol] = tt;
      }
    }
    if (HAVE_V) {
#pragma unroll
      for (int bl = 0; bl < 4; ++bl) {
        float dsum = 0.f;
        const float4* vp = (const float4*)(vsum + (size_t)(b0 + bl) * CO + c * OO + o0);
#pragma unroll
        for (int q = 0; q < 4; ++q) {
          float4 v4 = vp[q];
          dsum = fmaf(v4.x, tv[bl][4*q+0], dsum);
          dsum = fmaf(v4.y, tv[bl][4*q+1], dsum);
          dsum = fmaf(v4.z, tv[bl][4*q+2], dsum);
          dsum = fmaf(v4.w, tv[bl][4*q+3], dsum);
        }
        dsum += __shfl_xor(dsum, 32);
        float mm = dsum;
#pragma unroll
        for (int s = 16; s >= 1; s >>= 1) mm = fmaxf(mm, __shfl_xor(mm, s));
        float e = __expf(dsum - mm);
        float den = e;
#pragma unroll
        for (int s = 16; s >= 1; s >>= 1) den += __shfl_xor(den, s);
        float coef = e / den;
#pragma unroll
        for (int ol = 0; ol < 16; ++ol)
          acc[bl][ol] = fmaf(coef, tv[bl][ol], acc[bl][ol]);
      }
    }
  }
  const float cs = HAVE_V ? 1.f : 0.03125f;
#pragma unroll
  for (int bl = 0; bl < 4; ++bl) {
    float* pp = partial + ((size_t)jt * BB + (b0 + bl)) * CO + c * OO + o0;
#pragma unroll
    for (int q = 0; q < 4; ++q) {
      float4 w4 = make_float4(acc[bl][4*q+0]*cs, acc[bl][4*q+1]*cs,
                              acc[bl][4*q+2]*cs, acc[bl][4*q+3]*cs);
      ((float4*)pp)[q] = w4;
    }
  }
}

// Sum NJT bf16 j-tile partials -> s[b,c,o]; squash over o; vsum / out.
__global__ __launch_bounds__(256, 1) void reduce_squash_bf(
    const ushort_t* __restrict__ partial, float* __restrict__ vsum,
    float* __restrict__ out, int mode)   // 0: vsum = v; 1: vsum += v; 2: out = v
{
  const int idx = blockIdx.x * 256 + threadIdx.x;   // = b*CO + c*OO + o
  float s0 = 0.f, s1 = 0.f, s2 = 0.f, s3 = 0.f;
#pragma unroll 4
  for (int nt = 0; nt < NJT; nt += 4) {
    s0 += bf2f(partial[(size_t)(nt + 0) * (BB * CO) + idx]);
    s1 += bf2f(partial[(size_t)(nt + 1) * (BB * CO) + idx]);
    s2 += bf2f(partial[(size_t)(nt + 2) * (BB * CO) + idx]);
    s3 += bf2f(partial[(size_t)(nt + 3) * (BB * CO) + idx]);
  }
  float s = (s0 + s1) + (s2 + s3);
  float s2m = s * s;
#pragma unroll
  for (int mk = 16; mk >= 1; mk >>= 1) s2m += __shfl_xor(s2m, mk);
  float scale = s2m / ((1.f + s2m) * sqrtf(s2m + 1e-7f));
  float v = scale * s;
  if (mode == 2)      out[idx] = v;
  else if (mode == 1) vsum[idx] += v;
  else                vsum[idx] = v;
}

// f32 reduce for the fallback path
template<int NJTR>
__global__ __launch_bounds__(256, 1) void reduce_squash(
    const float* __restrict__ partial, float* __restrict__ vsum,
    float* __restrict__ out, int mode)
{
  const int idx = blockIdx.x * 256 + threadIdx.x;
  float s0 = 0.f, s1 = 0.f, s2 = 0.f, s3 = 0.f;
#pragma unroll 4
  for (int nt = 0; nt < NJTR; nt += 4) {
    s0 += partial[(size_t)(nt + 0) * (BB * CO) + idx];
    s1 += partial[(size_t)(nt + 1) * (BB * CO) + idx];
    s2 += partial[(size_t)(nt + 2) * (BB * CO) + idx];
    s3 += partial[(size_t)(nt + 3) * (BB * CO) + idx];
  }
  float s = (s0 + s1) + (s2 + s3);
  float s2m = s * s;
#pragma unroll
  for (int mk = 16; mk >= 1; mk >>= 1) s2m += __shfl_xor(s2m, mk);
  float scale = s2m / ((1.f + s2m) * sqrtf(s2m + 1e-7f));
  float v = scale * s;
  if (mode == 2)      out[idx] = v;
  else if (mode == 1) vsum[idx] += v;
  else                vsum[idx] = v;
}

static void run_mfma(const float* X, const float* W, float* out,
                     void* d_ws, hipStream_t stream)
{
  uint2* W2         = (uint2*)d_ws;
  uint2* X3         = (uint2*)((char*)d_ws + W2_BYTES);
  ushort_t* partial = (ushort_t*)((char*)d_ws + W2_BYTES + X3_BYTES);
  float* vsum       = (float*)((char*)d_ws + W2_BYTES + X3_BYTES
                               + (size_t)NJT * BB * CO * 2);
  const int grid  = NJT * 2;         // 256 blocks of 1024
  const int rgrid = BB * CO / 256;

  prep_w<<<JJ, 256, 0, stream>>>(W, W2);
  prep_x<<<2048, 256, 0, stream>>>(X, X3);

  route_pair<false><<<grid, 1024, 0, stream>>>((const uint4*)X3, (const uint4*)W2, nullptr, partial);
  reduce_squash_bf<<<rgrid, 256, 0, stream>>>(partial, vsum, nullptr, 0);

  route_pair<true><<<grid, 1024, 0, stream>>>((const uint4*)X3, (const uint4*)W2, vsum, partial);
  reduce_squash_bf<<<rgrid, 256, 0, stream>>>(partial, vsum, nullptr, 1);

  route_pair<true><<<grid, 1024, 0, stream>>>((const uint4*)X3, (const uint4*)W2, vsum, partial);
  reduce_squash_bf<<<rgrid, 256, 0, stream>>>(partial, vsum, out, 2);
}

static void run_f32_fallback(const float* X, const float* W, float* out,
                             void* d_ws, hipStream_t stream)
{
  float* partial = (float*)d_ws;
  float* vsum    = partial + (size_t)64 * BB * CO;
  const int grid  = 64 * 4;
  const int rgrid = BB * CO / 256;

  route_f32<false><<<grid, 256, 0, stream>>>(X, W, nullptr, partial);
  reduce_squash<64><<<rgrid, 256, 0, stream>>>(partial, vsum, nullptr, 0);
  route_f32<true><<<grid, 256, 0, stream>>>(X, W, vsum, partial);
  reduce_squash<64><<<rgrid, 256, 0, stream>>>(partial, vsum, nullptr, 1);
  route_f32<true><<<grid, 256, 0, stream>>>(X, W, vsum, partial);
  reduce_squash<64><<<rgrid, 256, 0, stream>>>(partial, vsum, out, 2);
}

extern "C" void kernel_launch(void* const* d_in, const int* in_sizes, int n_in,
                              void* d_out, int out_size, void* d_ws, size_t ws_size,
                              hipStream_t stream) {
  (void)in_sizes; (void)n_in; (void)out_size;
  const float* X = (const float*)d_in[0];   // x [64,2048,16] f32
  const float* W = (const float*)d_in[1];   // W [32,2048,32,16] f32
  float* out = (float*)d_out;               // v [64,32,32] f32

  const size_t need = W2_BYTES + X3_BYTES
                    + (size_t)NJT * BB * CO * 2 + (size_t)BB * CO * 4;
  if (ws_size >= need) run_mfma(X, W, out, d_ws, stream);
  else                 run_f32_fallback(X, W, out, d_ws, stream);
}

// Round 19
// 148.590 us; speedup vs baseline: 1.5896x; 1.5896x over previous
//
#include <hip/hip_runtime.h>
#include <hip/hip_bf16.h>
#include <stdint.h>

// Problem constants
#define BB 64      // batch
#define JJ 2048    // input capsules
#define DI 16      // input dim
#define CC 32      // output capsules
#define OO 32      // output dim
#define CO 1024    // CC*OO
#define TJ 16      // j per block
#define NJT 128    // JJ/TJ

static const size_t W2_BYTES = (size_t)CC * JJ * OO * DI * 2;  // 64 MB
static const size_t X3_BYTES = (size_t)BB * JJ * DI * 2;       // 4 MB

typedef _Float16 f16x4 __attribute__((ext_vector_type(4)));
typedef float    f32x4 __attribute__((ext_vector_type(4)));
typedef unsigned short ushort_t;

// __has_builtin on amdgcn builtins is false in the host pass (R7 lesson).
#if defined(__HIP_DEVICE_COMPILE__)
# if __has_builtin(__builtin_amdgcn_mfma_f32_16x16x16f16)
#  define MFMA16(a, b, c) __builtin_amdgcn_mfma_f32_16x16x16f16((a), (b), (c), 0, 0, 0)
# else
#  define MFMA16(a, b, c) __builtin_amdgcn_mfma_f32_16x16x16_f16((a), (b), (c), 0, 0, 0)
# endif
# define SCHED_FENCE() __builtin_amdgcn_sched_barrier(0)
#else
# define MFMA16(a, b, c) (c)
# define SCHED_FENCE()
#endif

// Pin waves/EU to exactly 4 (128-VGPR budget) — launch_bounds(…,4) is only a
// MIN hint and the allocator still targeted 8 waves/EU (64 VGPR) -> spills
// (R18: VGPR=64, 130 MB/pass scratch traffic).
#if __has_attribute(amdgpu_waves_per_eu)
# define WAVES4 __attribute__((amdgpu_waves_per_eu(4, 4)))
#else
# define WAVES4
#endif

union Pack2 { unsigned u; _Float16 h[2]; };

__device__ __forceinline__ ushort_t f2bf(float f) {   // RNE f32 -> bf16
  unsigned u = __float_as_uint(f);
  u += 0x7FFFu + ((u >> 16) & 1u);
  return (ushort_t)(u >> 16);
}
__device__ __forceinline__ float bf2f(ushort_t b) {
  return __uint_as_float(((unsigned)b) << 16);
}

// W [c][j][o][i] f32 -> W2 f16 in A-fragment order (A = W, rows = co, k = i):
// entry s = ct*64 + l of slab j holds W[co = ct*16 + (l&15)][i = 4*(l>>4)+e].
__global__ __launch_bounds__(256) void prep_w(const float* __restrict__ W,
                                              uint2* __restrict__ W2) {
  const int j = blockIdx.x;    // 2048
  const int tt = threadIdx.x;  // 256
#pragma unroll
  for (int r = 0; r < 16; ++r) {
    const int s = r * 256 + tt;           // 0..4095 = ct*64 + l
    const int ct = s >> 6, l = s & 63;
    const int co = ct * 16 + (l & 15);
    const int c = co >> 5, o = co & 31;
    const float4 src = ((const float4*)W)[(((size_t)c * JJ + j) * OO + o) * 4 + (l >> 4)];
    Pack2 a, b;
    a.h[0] = (_Float16)src.x; a.h[1] = (_Float16)src.y;
    b.h[0] = (_Float16)src.z; b.h[1] = (_Float16)src.w;
    W2[(size_t)j * 4096 + s] = make_uint2(a.u, b.u);
  }
}

// x [b][j][i] f32 -> X3 f16 in B-fragment order (B = x, cols = b, k = i).
__global__ __launch_bounds__(256) void prep_x(const float* __restrict__ X,
                                              uint2* __restrict__ X3) {
  const unsigned T = blockIdx.x * 256 + threadIdx.x;   // 524288
  const int l = T & 63, bt = (T >> 6) & 1, j = (T >> 7) & 2047, bq = (int)(T >> 18);
  const int b = bq * 32 + bt * 16 + (l & 15);
  const float4 src = ((const float4*)X)[((size_t)b * JJ + j) * 4 + (l >> 4)];
  Pack2 a, bb;
  a.h[0] = (_Float16)src.x; a.h[1] = (_Float16)src.y;
  bb.h[0] = (_Float16)src.z; bb.h[1] = (_Float16)src.w;
  X3[T] = make_uint2(a.u, bb.u);
}

// R19: R17 route + WAVE-PRIVATE staging. Wave w's A-frag read region of each
// slab is uint2 [w*256, w*256+256) == uint4 [w*128, +128) — a wave-private
// 2 KB block. Each wave stages ONLY its own region (2 global_load_lds), so:
//  - wbuf has NO cross-wave hazards; a wave's own counted vmcnt proves its
//    data landed -> the top-of-loop barrier is DELETED.
//  - pass 0 runs barrier-free after the prologue; HAVE_V has 2 barriers/jj
//    (logit, coef) instead of 3.
// vmcnt schedule unchanged (2 instr/slab/wave): vmcnt(4) steady, 2, 0 at tail.
// lbuf parity-dbuf: jj's write and jj-2's read are separated by jj-1's
// logit+coef barriers. Grid NJT*2 = 256 blocks of 1024 (16 waves, 1 blk/CU).
template<bool HAVE_V>
__global__ __launch_bounds__(1024, 4) WAVES4 void route_mfma(
    const uint4* __restrict__ X3, const uint4* __restrict__ W2,
    const float* __restrict__ vsum, ushort_t* __restrict__ partial)
{
  __shared__ uint4 wbuf[4][2048];    // 4 x 32KB W slabs (A-frags)
  __shared__ uint4 xbuf[1024];       // 16KB x B-frags
  __shared__ float lbuf[2][32 * 33]; // 32 b-rows x 32 c (+1 pad), jj-parity dbuf

  const int jt   = blockIdx.x & (NJT - 1);
  const int bq   = blockIdx.x >> 7;
  const int tid  = threadIdx.x;
  const int w    = tid >> 6;
  const int lane = tid & 63;
  const int g    = lane >> 4;
  const int t    = lane & 15;

  // vsum[b][c][o] packed f16 pairs (16 VGPR). Loaded + converted BEFORE any
  // stage issue, then vmcnt(0)-fenced so the manual stage counts stay exact.
  unsigned vsh[2][2][2][2];   // [cc][bt][hh][rp]
  if (HAVE_V) {
#pragma unroll
    for (int cc = 0; cc < 2; ++cc)
#pragma unroll
      for (int bt = 0; bt < 2; ++bt)
#pragma unroll
        for (int hh = 0; hh < 2; ++hh)
#pragma unroll
          for (int rp = 0; rp < 2; ++rp) {
            const float* vp = vsum + (size_t)(bq * 32 + bt * 16 + t) * CO
                            + (2 * w + cc) * OO + hh * 16 + 4 * g + 2 * rp;
            Pack2 p; p.h[0] = (_Float16)vp[0]; p.h[1] = (_Float16)vp[1];
            vsh[cc][bt][hh][rp] = p.u;
          }
    asm volatile("s_waitcnt vmcnt(0)" ::: "memory");
  }

  const uint4* wsrc = W2 + (size_t)jt * TJ * 2048;   // 16B units, 2048/j

  // Wave-private stage: wave w stages its own uint4 region [w*128, w*128+128)
  // of the slab (2 instrs x 64 lanes x 16B). Dest = wave-uniform base +
  // lane*16 (contiguous) — satisfies global_load_lds addressing.
#define STAGEW(bufidx, slab) do {                                                 \
    const uint4* sp_ = wsrc + (size_t)(slab) * 2048 + w * 128 + lane;             \
    uint4* dp_ = &wbuf[bufidx][w * 128 + lane];                                   \
    _Pragma("unroll")                                                             \
    for (int r_ = 0; r_ < 2; ++r_)                                                \
      __builtin_amdgcn_global_load_lds(                                           \
          (const __attribute__((address_space(1))) void*)(sp_ + r_ * 64),         \
          (__attribute__((address_space(3))) void*)(dp_ + r_ * 64), 16, 0, 0);    \
  } while (0)

  // prologue: x B-frags (all-wave shared; 1 instr/thread) + slabs 0..2.
  {
    const uint4* xs = X3 + ((size_t)bq * JJ + jt * TJ) * 64 + tid;   // 16B units
    __builtin_amdgcn_global_load_lds(
        (const __attribute__((address_space(1))) void*)xs,
        (__attribute__((address_space(3))) void*)&xbuf[tid], 16, 0, 0);
  }
  STAGEW(0, 0);
  STAGEW(1, 1);
  STAGEW(2, 2);
  // drain xbuf (oldest = 1 instr; 6 slab instrs remain) then sync: xbuf is
  // read by ALL waves, so it needs the one prologue barrier.
  asm volatile("s_waitcnt vmcnt(6)" ::: "memory");
  SCHED_FENCE();
  __builtin_amdgcn_s_barrier();

  f32x4 acc[4][2];
#pragma unroll
  for (int k = 0; k < 4; ++k)
#pragma unroll
    for (int bt = 0; bt < 2; ++bt) acc[k][bt] = f32x4{0.f, 0.f, 0.f, 0.f};

  for (int jj = 0; jj < TJ; ++jj) {
    const int bcur = jj & 3;
    // own slab-jj region landed; keep jj+1, jj+2 (2 instr each) in flight.
    if (jj < TJ - 2)       asm volatile("s_waitcnt vmcnt(4)" ::: "memory");
    else if (jj == TJ - 2) asm volatile("s_waitcnt vmcnt(2)" ::: "memory");
    else                   asm volatile("s_waitcnt vmcnt(0)" ::: "memory");
    SCHED_FENCE();
    // no barrier: wbuf region is wave-private (reads below touch only the
    // region this wave staged; overwrite target below was last read by this
    // wave 4 iterations ago, drained by its own lgkm waits).
    if (jj + 3 < TJ) STAGEW((jj + 3) & 3, jj + 3);

    const uint2* wb2 = (const uint2*)wbuf[bcur];
    const uint2* xb2 = (const uint2*)xbuf;

    f16x4 bf[2];
#pragma unroll
    for (int bt = 0; bt < 2; ++bt)
      bf[bt] = __builtin_bit_cast(f16x4, xb2[(jj * 2 + bt) * 64 + lane]);
    f16x4 af[4];
#pragma unroll
    for (int k = 0; k < 4; ++k)
      af[k] = __builtin_bit_cast(f16x4, wb2[(w * 4 + k) * 64 + lane]);

    f32x4 uh[4][2];
#pragma unroll
    for (int k = 0; k < 4; ++k)
#pragma unroll
      for (int bt = 0; bt < 2; ++bt) {
        if (HAVE_V) uh[k][bt] = MFMA16(af[k], bf[bt], (f32x4{0.f, 0.f, 0.f, 0.f}));
        else        acc[k][bt] = MFMA16(af[k], bf[bt], acc[k][bt]);
      }

    if (HAVE_V) {
      // logit[b][c] partials over this lane's 8 o's, then sum over g (xor16/32)
      float lp[2][2];
#pragma unroll
      for (int cc = 0; cc < 2; ++cc)
#pragma unroll
        for (int bt = 0; bt < 2; ++bt) {
          float s = 0.f;
#pragma unroll
          for (int hh = 0; hh < 2; ++hh)
#pragma unroll
            for (int rp = 0; rp < 2; ++rp) {
              Pack2 p; p.u = vsh[cc][bt][hh][rp];
              s = fmaf(uh[2 * cc + hh][bt][2 * rp],     (float)p.h[0], s);
              s = fmaf(uh[2 * cc + hh][bt][2 * rp + 1], (float)p.h[1], s);
            }
          s += __shfl_xor(s, 16);
          s += __shfl_xor(s, 32);
          lp[cc][bt] = s;
        }
      // each lane writes combo (cc = g>>1, bt = g&1) -> static-index select
      {
        const float hi = (g & 1) ? lp[1][1] : lp[1][0];
        const float lo = (g & 1) ? lp[0][1] : lp[0][0];
        const float val = (g >> 1) ? hi : lo;
        lbuf[jj & 1][((g & 1) * 16 + t) * 33 + 2 * w + (g >> 1)] = val;
      }
      asm volatile("s_waitcnt lgkmcnt(0)" ::: "memory");
      SCHED_FENCE();
      __builtin_amdgcn_s_barrier();

      // row softmax (|logit| small, f32 exp safe); wave w owns rows 2w, 2w+1
      {
        const int row = 2 * w + (lane >> 5);
        const int cc2 = lane & 31;
        float e = __expf(lbuf[jj & 1][row * 33 + cc2]);
        float den = e;
        den += __shfl_xor(den, 1);  den += __shfl_xor(den, 2);
        den += __shfl_xor(den, 4);  den += __shfl_xor(den, 8);
        den += __shfl_xor(den, 16);
        lbuf[jj & 1][row * 33 + cc2] = e / den;
      }
      asm volatile("s_waitcnt lgkmcnt(0)" ::: "memory");
      SCHED_FENCE();
      __builtin_amdgcn_s_barrier();

      float cf[2][2];
#pragma unroll
      for (int cc = 0; cc < 2; ++cc)
#pragma unroll
        for (int bt = 0; bt < 2; ++bt)
          cf[cc][bt] = lbuf[jj & 1][(bt * 16 + t) * 33 + 2 * w + cc];
#pragma unroll
      for (int k = 0; k < 4; ++k)
#pragma unroll
        for (int bt = 0; bt < 2; ++bt)
#pragma unroll
          for (int r = 0; r < 4; ++r)
            acc[k][bt][r] = fmaf(cf[k >> 1][bt], uh[k][bt][r], acc[k][bt][r]);
      // next jj writes lbuf[(jj+1)&1] (parity dbuf)
    }
  }
#undef STAGEW

  // D layout: col = t -> b, rows = 4g + r -> co: acc[k][bt] is 4 consecutive
  // co -> bf16 ushort4 store (8B), halves partial traffic.
  const float cs = HAVE_V ? 1.f : 0.03125f;
#pragma unroll
  for (int k = 0; k < 4; ++k)
#pragma unroll
    for (int bt = 0; bt < 2; ++bt) {
      const int b  = bq * 32 + bt * 16 + t;
      const int co = (4 * w + k) * 16 + 4 * g;
      ushort4 v;
      v.x = f2bf(acc[k][bt][0] * cs);
      v.y = f2bf(acc[k][bt][1] * cs);
      v.z = f2bf(acc[k][bt][2] * cs);
      v.w = f2bf(acc[k][bt][3] * cs);
      *(ushort4*)(partial + ((size_t)jt * BB + b) * CO + co) = v;
    }
}

// ---------------- f32 fallback route (proven R2/R4 path) ----------------
template<bool HAVE_V>
__global__ __launch_bounds__(256, 1) void route_f32(
    const float* __restrict__ X, const float* __restrict__ W,
    const float* __restrict__ vsum, float* __restrict__ partial)
{
  const int jt   = blockIdx.x & 63;
  const int bq   = blockIdx.x >> 6;
  const int tid  = threadIdx.x;
  const int wave = tid >> 6;
  const int lane = tid & 63;
  const int c    = lane & 31;
  const int o0   = (lane >> 5) << 4;
  const int b0   = bq * 16 + wave * 4;

  float acc[4][16];
#pragma unroll
  for (int bl = 0; bl < 4; ++bl)
#pragma unroll
    for (int ol = 0; ol < 16; ++ol) acc[bl][ol] = 0.f;

  const float* wbase = W + ((size_t)c * JJ * OO + (size_t)o0) * DI;

  for (int jj = 0; jj < 32; ++jj) {
    const int j = jt * 32 + jj;
    float xf[4][16];
#pragma unroll
    for (int bl = 0; bl < 4; ++bl) {
      const float4* xpt = (const float4*)(X + ((size_t)(b0 + bl) * JJ + j) * DI);
#pragma unroll
      for (int q = 0; q < 4; ++q) {
        float4 x4 = xpt[q];
        xf[bl][4*q+0] = x4.x; xf[bl][4*q+1] = x4.y;
        xf[bl][4*q+2] = x4.z; xf[bl][4*q+3] = x4.w;
      }
    }
    const float4* wp = (const float4*)(wbase + (size_t)j * OO * DI);
    float tv[4][16];
#pragma unroll
    for (int ol = 0; ol < 16; ++ol) {
      float wf[16];
#pragma unroll
      for (int q = 0; q < 4; ++q) {
        float4 w4 = wp[4*ol + q];
        wf[4*q+0] = w4.x; wf[4*q+1] = w4.y;
        wf[4*q+2] = w4.z; wf[4*q+3] = w4.w;
      }
#pragma unroll
      for (int bl = 0; bl < 4; ++bl) {
        float tt = 0.f;
#pragma unroll
        for (int i = 0; i < 16; ++i) tt = fmaf(wf[i], xf[bl][i], tt);
        if (!HAVE_V) acc[bl][ol] += tt;
        else         tv[bl][ol] = tt;
      }
    }
    if (HAVE_V) {
#pragma unroll
      for (int bl = 0; bl < 4; ++bl) {
        float dsum = 0.f;
        const float4* vp = (const float4*)(vsum + (size_t)(b0 + bl) * CO + c * OO + o0);
#pragma unroll
        for (int q = 0; q < 4; ++q) {
          float4 v4 = vp[q];
          dsum = fmaf(v4.x, tv[bl][4*q+0], dsum);
          dsum = fmaf(v4.y, tv[bl][4*q+1], dsum);
          dsum = fmaf(v4.z, tv[bl][4*q+2], dsum);
          dsum = fmaf(v4.w, tv[bl][4*q+3], dsum);
        }
        dsum += __shfl_xor(dsum, 32);
        float mm = dsum;
#pragma unroll
        for (int s = 16; s >= 1; s >>= 1) mm = fmaxf(mm, __shfl_xor(mm, s));
        float e = __expf(dsum - mm);
        float den = e;
#pragma unroll
        for (int s = 16; s >= 1; s >>= 1) den += __shfl_xor(den, s);
        float coef = e / den;
#pragma unroll
        for (int ol = 0; ol < 16; ++ol)
          acc[bl][ol] = fmaf(coef, tv[bl][ol], acc[bl][ol]);
      }
    }
  }
  const float cs = HAVE_V ? 1.f : 0.03125f;
#pragma unroll
  for (int bl = 0; bl < 4; ++bl) {
    float* pp = partial + ((size_t)jt * BB + (b0 + bl)) * CO + c * OO + o0;
#pragma unroll
    for (int q = 0; q < 4; ++q) {
      float4 w4 = make_float4(acc[bl][4*q+0]*cs, acc[bl][4*q+1]*cs,
                              acc[bl][4*q+2]*cs, acc[bl][4*q+3]*cs);
      ((float4*)pp)[q] = w4;
    }
  }
}

// Sum NJT bf16 j-tile partials -> s[b,c,o]; squash over o; vsum / out.
__global__ __launch_bounds__(256, 1) void reduce_squash_bf(
    const ushort_t* __restrict__ partial, float* __restrict__ vsum,
    float* __restrict__ out, int mode)   // 0: vsum = v; 1: vsum += v; 2: out = v
{
  const int idx = blockIdx.x * 256 + threadIdx.x;   // = b*CO + c*OO + o
  float s0 = 0.f, s1 = 0.f, s2 = 0.f, s3 = 0.f;
#pragma unroll 4
  for (int nt = 0; nt < NJT; nt += 4) {
    s0 += bf2f(partial[(size_t)(nt + 0) * (BB * CO) + idx]);
    s1 += bf2f(partial[(size_t)(nt + 1) * (BB * CO) + idx]);
    s2 += bf2f(partial[(size_t)(nt + 2) * (BB * CO) + idx]);
    s3 += bf2f(partial[(size_t)(nt + 3) * (BB * CO) + idx]);
  }
  float s = (s0 + s1) + (s2 + s3);
  float s2m = s * s;
#pragma unroll
  for (int mk = 16; mk >= 1; mk >>= 1) s2m += __shfl_xor(s2m, mk);
  float scale = s2m / ((1.f + s2m) * sqrtf(s2m + 1e-7f));
  float v = scale * s;
  if (mode == 2)      out[idx] = v;
  else if (mode == 1) vsum[idx] += v;
  else                vsum[idx] = v;
}

// f32 reduce for the fallback path
template<int NJTR>
__global__ __launch_bounds__(256, 1) void reduce_squash(
    const float* __restrict__ partial, float* __restrict__ vsum,
    float* __restrict__ out, int mode)
{
  const int idx = blockIdx.x * 256 + threadIdx.x;
  float s0 = 0.f, s1 = 0.f, s2 = 0.f, s3 = 0.f;
#pragma unroll 4
  for (int nt = 0; nt < NJTR; nt += 4) {
    s0 += partial[(size_t)(nt + 0) * (BB * CO) + idx];
    s1 += partial[(size_t)(nt + 1) * (BB * CO) + idx];
    s2 += partial[(size_t)(nt + 2) * (BB * CO) + idx];
    s3 += partial[(size_t)(nt + 3) * (BB * CO) + idx];
  }
  float s = (s0 + s1) + (s2 + s3);
  float s2m = s * s;
#pragma unroll
  for (int mk = 16; mk >= 1; mk >>= 1) s2m += __shfl_xor(s2m, mk);
  float scale = s2m / ((1.f + s2m) * sqrtf(s2m + 1e-7f));
  float v = scale * s;
  if (mode == 2)      out[idx] = v;
  else if (mode == 1) vsum[idx] += v;
  else                vsum[idx] = v;
}

static void run_mfma(const float* X, const float* W, float* out,
                     void* d_ws, hipStream_t stream)
{
  uint2* W2         = (uint2*)d_ws;
  uint2* X3         = (uint2*)((char*)d_ws + W2_BYTES);
  ushort_t* partial = (ushort_t*)((char*)d_ws + W2_BYTES + X3_BYTES);
  float* vsum       = (float*)((char*)d_ws + W2_BYTES + X3_BYTES
                               + (size_t)NJT * BB * CO * 2);
  const int grid  = NJT * 2;         // 256 blocks of 1024
  const int rgrid = BB * CO / 256;

  prep_w<<<JJ, 256, 0, stream>>>(W, W2);
  prep_x<<<2048, 256, 0, stream>>>(X, X3);

  route_mfma<false><<<grid, 1024, 0, stream>>>((const uint4*)X3, (const uint4*)W2, nullptr, partial);
  reduce_squash_bf<<<rgrid, 256, 0, stream>>>(partial, vsum, nullptr, 0);

  route_mfma<true><<<grid, 1024, 0, stream>>>((const uint4*)X3, (const uint4*)W2, vsum, partial);
  reduce_squash_bf<<<rgrid, 256, 0, stream>>>(partial, vsum, nullptr, 1);

  route_mfma<true><<<grid, 1024, 0, stream>>>((const uint4*)X3, (const uint4*)W2, vsum, partial);
  reduce_squash_bf<<<rgrid, 256, 0, stream>>>(partial, vsum, out, 2);
}

static void run_f32_fallback(const float* X, const float* W, float* out,
                             void* d_ws, hipStream_t stream)
{
  float* partial = (float*)d_ws;
  float* vsum    = partial + (size_t)64 * BB * CO;
  const int grid  = 64 * 4;
  const int rgrid = BB * CO / 256;

  route_f32<false><<<grid, 256, 0, stream>>>(X, W, nullptr, partial);
  reduce_squash<64><<<rgrid, 256, 0, stream>>>(partial, vsum, nullptr, 0);
  route_f32<true><<<grid, 256, 0, stream>>>(X, W, vsum, partial);
  reduce_squash<64><<<rgrid, 256, 0, stream>>>(partial, vsum, nullptr, 1);
  route_f32<true><<<grid, 256, 0, stream>>>(X, W, vsum, partial);
  reduce_squash<64><<<rgrid, 256, 0, stream>>>(partial, vsum, out, 2);
}

extern "C" void kernel_launch(void* const* d_in, const int* in_sizes, int n_in,
                              void* d_out, int out_size, void* d_ws, size_t ws_size,
                              hipStream_t stream) {
  (void)in_sizes; (void)n_in; (void)out_size;
  const float* X = (const float*)d_in[0];   // x [64,2048,16] f32
  const float* W = (const float*)d_in[1];   // W [32,2048,32,16] f32
  float* out = (float*)d_out;               // v [64,32,32] f32

  const size_t need = W2_BYTES + X3_BYTES
                    + (size_t)NJT * BB * CO * 2 + (size_t)BB * CO * 4;
  if (ws_size >= need) run_mfma(X, W, out, d_ws, stream);
  else                 run_f32_fallback(X, W, out, d_ws, stream);
}

// Round 20
// 136.912 us; speedup vs baseline: 1.7252x; 1.0853x over previous
//
#include <hip/hip_runtime.h>
#include <hip/hip_bf16.h>
#include <stdint.h>

// Problem constants
#define BB 64      // batch
#define JJ 2048    // input capsules
#define DI 16      // input dim
#define CC 32      // output capsules
#define OO 32      // output dim
#define CO 1024    // CC*OO
#define TJ 16      // j per block
#define NJT 128    // JJ/TJ

static const size_t W2_BYTES = (size_t)CC * JJ * OO * DI * 2;  // 64 MB
static const size_t X3_BYTES = (size_t)BB * JJ * DI * 2;       // 4 MB

typedef _Float16 f16x4 __attribute__((ext_vector_type(4)));
typedef float    f32x4 __attribute__((ext_vector_type(4)));
typedef unsigned short ushort_t;

// __has_builtin on amdgcn builtins is false in the host pass (R7 lesson).
#if defined(__HIP_DEVICE_COMPILE__)
# if __has_builtin(__builtin_amdgcn_mfma_f32_16x16x16f16)
#  define MFMA16(a, b, c) __builtin_amdgcn_mfma_f32_16x16x16f16((a), (b), (c), 0, 0, 0)
# else
#  define MFMA16(a, b, c) __builtin_amdgcn_mfma_f32_16x16x16_f16((a), (b), (c), 0, 0, 0)
# endif
# define SCHED_FENCE() __builtin_amdgcn_sched_barrier(0)
#else
# define MFMA16(a, b, c) (c)
# define SCHED_FENCE()
#endif

#if __has_attribute(amdgpu_waves_per_eu)
# define WAVES4 __attribute__((amdgpu_waves_per_eu(4, 4)))
#else
# define WAVES4
#endif

union Pack2 { unsigned u; _Float16 h[2]; };

__device__ __forceinline__ ushort_t f2bf(float f) {   // RNE f32 -> bf16
  unsigned u = __float_as_uint(f);
  u += 0x7FFFu + ((u >> 16) & 1u);
  return (ushort_t)(u >> 16);
}
__device__ __forceinline__ float bf2f(ushort_t b) {
  return __uint_as_float(((unsigned)b) << 16);
}

// x [b][j][i] f32 -> X3 f16 in B-fragment order (B = x, cols = b, k = i).
__global__ __launch_bounds__(256) void prep_x(const float* __restrict__ X,
                                              uint2* __restrict__ X3) {
  const unsigned T = blockIdx.x * 256 + threadIdx.x;   // 524288
  const int l = T & 63, bt = (T >> 6) & 1, j = (T >> 7) & 2047, bq = (int)(T >> 18);
  const int b = bq * 32 + bt * 16 + (l & 15);
  const float4 src = ((const float4*)X)[((size_t)b * JJ + j) * 4 + (l >> 4)];
  Pack2 a, bb;
  a.h[0] = (_Float16)src.x; a.h[1] = (_Float16)src.y;
  bb.h[0] = (_Float16)src.z; bb.h[1] = (_Float16)src.w;
  X3[T] = make_uint2(a.u, bb.u);
}

// R20 pass 0: convert + route fused. Stages W f32 DIRECTLY from its natural
// [c][j][o][i] layout using per-lane DMA source addresses (the fragment
// gather is a contiguous 1 KB region per wave-instruction -> coalesced).
// ds_read f32 frags -> cvt f16 -> MFMA; bq==0 blocks store converted frags
// to W2 for passes 1-2. No lbuf, no in-loop barriers (wave-private W
// regions; xbuf needs only the prologue barrier). 2 f32 slabs (128 KB),
// depth-1 prefetch; stores count in vmcnt so the last 2 iters drain fully.
__global__ __launch_bounds__(1024, 4) WAVES4 void route_conv(
    const uint4* __restrict__ X3, const float* __restrict__ Wf,
    uint2* __restrict__ W2out, ushort_t* __restrict__ partial)
{
  __shared__ uint4 wbuf32[2][4096];  // 2 x 64KB f32 A-frag slabs
  __shared__ uint4 xbuf[1024];       // 16KB x B-frags

  const int jt   = blockIdx.x & (NJT - 1);
  const int bq   = blockIdx.x >> 7;
  const int tid  = threadIdx.x;
  const int w    = tid >> 6;
  const int lane = tid & 63;
  const int g    = lane >> 4;
  const int t    = lane & 15;

  // Wave-private f32 stage: instr r covers tile ct = w*4+r; the 64 lanes'
  // sources are one contiguous 1KB row-block of W; dest = linear lane*16.
  // src uint4 idx = ((ct>>1)*JJ + j)*128 + (ct&1)*64 + (lane&15)*4 + (lane>>4)
#define STAGEC(slot, jjv) do {                                                    \
    const int j_ = jt * TJ + (jjv);                                               \
    _Pragma("unroll")                                                             \
    for (int r_ = 0; r_ < 4; ++r_) {                                              \
      const int ct_ = w * 4 + r_;                                                 \
      const uint4* sp_ = (const uint4*)Wf                                         \
          + ((size_t)(ct_ >> 1) * JJ + j_) * 128 + (ct_ & 1) * 64                 \
          + (lane & 15) * 4 + (lane >> 4);                                        \
      uint4* dp_ = &wbuf32[slot][w * 256 + r_ * 64 + lane];                       \
      __builtin_amdgcn_global_load_lds(                                           \
          (const __attribute__((address_space(1))) void*)sp_,                     \
          (__attribute__((address_space(3))) void*)dp_, 16, 0, 0);                \
    }                                                                             \
  } while (0)

  // prologue: x B-frags + slabs 0,1
  {
    const uint4* xs = X3 + ((size_t)bq * JJ + jt * TJ) * 64 + tid;
    __builtin_amdgcn_global_load_lds(
        (const __attribute__((address_space(1))) void*)xs,
        (__attribute__((address_space(3))) void*)&xbuf[tid], 16, 0, 0);
  }
  STAGEC(0, 0);
  STAGEC(1, 1);
  asm volatile("s_waitcnt vmcnt(8)" ::: "memory");   // xbuf (oldest) landed
  SCHED_FENCE();
  __builtin_amdgcn_s_barrier();

  f32x4 acc[4][2];
#pragma unroll
  for (int k = 0; k < 4; ++k)
#pragma unroll
    for (int bt = 0; bt < 2; ++bt) acc[k][bt] = f32x4{0.f, 0.f, 0.f, 0.f};

  for (int jj = 0; jj < TJ; ++jj) {
    const int bcur = jj & 1;
    // slab jj landed. Steady state: newest 4 = slab jj+1 stay in flight
    // (W2 stores are older than the newest stage -> also drained, safe).
    if (jj < TJ - 2) asm volatile("s_waitcnt vmcnt(4)" ::: "memory");
    else             asm volatile("s_waitcnt vmcnt(0)" ::: "memory");
    SCHED_FENCE();

    const uint2* xb2 = (const uint2*)xbuf;
    f16x4 bf[2];
#pragma unroll
    for (int bt = 0; bt < 2; ++bt)
      bf[bt] = __builtin_bit_cast(f16x4, xb2[(jj * 2 + bt) * 64 + lane]);

    const f32x4* wr = (const f32x4*)wbuf32[bcur];
    f16x4 af[4];
#pragma unroll
    for (int k = 0; k < 4; ++k) {
      f32x4 a32 = wr[w * 256 + k * 64 + lane];
      af[k][0] = (_Float16)a32[0]; af[k][1] = (_Float16)a32[1];
      af[k][2] = (_Float16)a32[2]; af[k][3] = (_Float16)a32[3];
    }

    // store converted fragments to W2 (only bq==0; identical data otherwise)
    if (bq == 0) {
      const size_t wbase = (size_t)(jt * TJ + jj) * 4096;
#pragma unroll
      for (int k = 0; k < 4; ++k) {
        Pack2 p0, p1;
        p0.h[0] = af[k][0]; p0.h[1] = af[k][1];
        p1.h[0] = af[k][2]; p1.h[1] = af[k][3];
        W2out[wbase + (w * 4 + k) * 64 + lane] = make_uint2(p0.u, p1.u);
      }
    }

#pragma unroll
    for (int k = 0; k < 4; ++k)
#pragma unroll
      for (int bt = 0; bt < 2; ++bt)
        acc[k][bt] = MFMA16(af[k], bf[bt], acc[k][bt]);

    // own ds_reads retired -> safe to overwrite this slot
    asm volatile("s_waitcnt lgkmcnt(0)" ::: "memory");
    SCHED_FENCE();
    if (jj + 2 < TJ) STAGEC(bcur, jj + 2);
  }
#undef STAGEC

  // uniform coef 1/32; bf16 partial store
#pragma unroll
  for (int k = 0; k < 4; ++k)
#pragma unroll
    for (int bt = 0; bt < 2; ++bt) {
      const int b  = bq * 32 + bt * 16 + t;
      const int co = (4 * w + k) * 16 + 4 * g;
      ushort4 v;
      v.x = f2bf(acc[k][bt][0] * 0.03125f);
      v.y = f2bf(acc[k][bt][1] * 0.03125f);
      v.z = f2bf(acc[k][bt][2] * 0.03125f);
      v.w = f2bf(acc[k][bt][3] * 0.03125f);
      *(ushort4*)(partial + ((size_t)jt * BB + b) * CO + co) = v;
    }
}

// R19 HAVE_V route (proven at 148.6 us): wave-private f16 staging, no top
// barrier, 2 barriers/jj (logit, coef), parity-dbuf lbuf, bf16 partial.
__global__ __launch_bounds__(1024, 4) WAVES4 void route_v(
    const uint4* __restrict__ X3, const uint4* __restrict__ W2,
    const float* __restrict__ vsum, ushort_t* __restrict__ partial)
{
  __shared__ uint4 wbuf[4][2048];    // 4 x 32KB W slabs (A-frags)
  __shared__ uint4 xbuf[1024];       // 16KB x B-frags
  __shared__ float lbuf[2][32 * 33];

  const int jt   = blockIdx.x & (NJT - 1);
  const int bq   = blockIdx.x >> 7;
  const int tid  = threadIdx.x;
  const int w    = tid >> 6;
  const int lane = tid & 63;
  const int g    = lane >> 4;
  const int t    = lane & 15;

  unsigned vsh[2][2][2][2];   // [cc][bt][hh][rp]
#pragma unroll
  for (int cc = 0; cc < 2; ++cc)
#pragma unroll
    for (int bt = 0; bt < 2; ++bt)
#pragma unroll
      for (int hh = 0; hh < 2; ++hh)
#pragma unroll
        for (int rp = 0; rp < 2; ++rp) {
          const float* vp = vsum + (size_t)(bq * 32 + bt * 16 + t) * CO
                          + (2 * w + cc) * OO + hh * 16 + 4 * g + 2 * rp;
          Pack2 p; p.h[0] = (_Float16)vp[0]; p.h[1] = (_Float16)vp[1];
          vsh[cc][bt][hh][rp] = p.u;
        }
  asm volatile("s_waitcnt vmcnt(0)" ::: "memory");

  const uint4* wsrc = W2 + (size_t)jt * TJ * 2048;

#define STAGEW(bufidx, slab) do {                                                 \
    const uint4* sp_ = wsrc + (size_t)(slab) * 2048 + w * 128 + lane;             \
    uint4* dp_ = &wbuf[bufidx][w * 128 + lane];                                   \
    _Pragma("unroll")                                                             \
    for (int r_ = 0; r_ < 2; ++r_)                                                \
      __builtin_amdgcn_global_load_lds(                                           \
          (const __attribute__((address_space(1))) void*)(sp_ + r_ * 64),         \
          (__attribute__((address_space(3))) void*)(dp_ + r_ * 64), 16, 0, 0);    \
  } while (0)

  {
    const uint4* xs = X3 + ((size_t)bq * JJ + jt * TJ) * 64 + tid;
    __builtin_amdgcn_global_load_lds(
        (const __attribute__((address_space(1))) void*)xs,
        (__attribute__((address_space(3))) void*)&xbuf[tid], 16, 0, 0);
  }
  STAGEW(0, 0);
  STAGEW(1, 1);
  STAGEW(2, 2);
  asm volatile("s_waitcnt vmcnt(6)" ::: "memory");
  SCHED_FENCE();
  __builtin_amdgcn_s_barrier();

  f32x4 acc[4][2];
#pragma unroll
  for (int k = 0; k < 4; ++k)
#pragma unroll
    for (int bt = 0; bt < 2; ++bt) acc[k][bt] = f32x4{0.f, 0.f, 0.f, 0.f};

  for (int jj = 0; jj < TJ; ++jj) {
    const int bcur = jj & 3;
    if (jj < TJ - 2)       asm volatile("s_waitcnt vmcnt(4)" ::: "memory");
    else if (jj == TJ - 2) asm volatile("s_waitcnt vmcnt(2)" ::: "memory");
    else                   asm volatile("s_waitcnt vmcnt(0)" ::: "memory");
    SCHED_FENCE();
    if (jj + 3 < TJ) STAGEW((jj + 3) & 3, jj + 3);

    const uint2* wb2 = (const uint2*)wbuf[bcur];
    const uint2* xb2 = (const uint2*)xbuf;

    f16x4 bf[2];
#pragma unroll
    for (int bt = 0; bt < 2; ++bt)
      bf[bt] = __builtin_bit_cast(f16x4, xb2[(jj * 2 + bt) * 64 + lane]);
    f16x4 af[4];
#pragma unroll
    for (int k = 0; k < 4; ++k)
      af[k] = __builtin_bit_cast(f16x4, wb2[(w * 4 + k) * 64 + lane]);

    f32x4 uh[4][2];
#pragma unroll
    for (int k = 0; k < 4; ++k)
#pragma unroll
      for (int bt = 0; bt < 2; ++bt)
        uh[k][bt] = MFMA16(af[k], bf[bt], (f32x4{0.f, 0.f, 0.f, 0.f}));

    float lp[2][2];
#pragma unroll
    for (int cc = 0; cc < 2; ++cc)
#pragma unroll
      for (int bt = 0; bt < 2; ++bt) {
        float s = 0.f;
#pragma unroll
        for (int hh = 0; hh < 2; ++hh)
#pragma unroll
          for (int rp = 0; rp < 2; ++rp) {
            Pack2 p; p.u = vsh[cc][bt][hh][rp];
            s = fmaf(uh[2 * cc + hh][bt][2 * rp],     (float)p.h[0], s);
            s = fmaf(uh[2 * cc + hh][bt][2 * rp + 1], (float)p.h[1], s);
          }
        s += __shfl_xor(s, 16);
        s += __shfl_xor(s, 32);
        lp[cc][bt] = s;
      }
    {
      const float hi = (g & 1) ? lp[1][1] : lp[1][0];
      const float lo = (g & 1) ? lp[0][1] : lp[0][0];
      const float val = (g >> 1) ? hi : lo;
      lbuf[jj & 1][((g & 1) * 16 + t) * 33 + 2 * w + (g >> 1)] = val;
    }
    asm volatile("s_waitcnt lgkmcnt(0)" ::: "memory");
    SCHED_FENCE();
    __builtin_amdgcn_s_barrier();

    {
      const int row = 2 * w + (lane >> 5);
      const int cc2 = lane & 31;
      float e = __expf(lbuf[jj & 1][row * 33 + cc2]);
      float den = e;
      den += __shfl_xor(den, 1);  den += __shfl_xor(den, 2);
      den += __shfl_xor(den, 4);  den += __shfl_xor(den, 8);
      den += __shfl_xor(den, 16);
      lbuf[jj & 1][row * 33 + cc2] = e / den;
    }
    asm volatile("s_waitcnt lgkmcnt(0)" ::: "memory");
    SCHED_FENCE();
    __builtin_amdgcn_s_barrier();

    float cf[2][2];
#pragma unroll
    for (int cc = 0; cc < 2; ++cc)
#pragma unroll
      for (int bt = 0; bt < 2; ++bt)
        cf[cc][bt] = lbuf[jj & 1][(bt * 16 + t) * 33 + 2 * w + cc];
#pragma unroll
    for (int k = 0; k < 4; ++k)
#pragma unroll
      for (int bt = 0; bt < 2; ++bt)
#pragma unroll
        for (int r = 0; r < 4; ++r)
          acc[k][bt][r] = fmaf(cf[k >> 1][bt], uh[k][bt][r], acc[k][bt][r]);
  }
#undef STAGEW

#pragma unroll
  for (int k = 0; k < 4; ++k)
#pragma unroll
    for (int bt = 0; bt < 2; ++bt) {
      const int b  = bq * 32 + bt * 16 + t;
      const int co = (4 * w + k) * 16 + 4 * g;
      ushort4 v;
      v.x = f2bf(acc[k][bt][0]);
      v.y = f2bf(acc[k][bt][1]);
      v.z = f2bf(acc[k][bt][2]);
      v.w = f2bf(acc[k][bt][3]);
      *(ushort4*)(partial + ((size_t)jt * BB + b) * CO + co) = v;
    }
}

// ---------------- f32 fallback route (proven R2/R4 path) ----------------
template<bool HAVE_V>
__global__ __launch_bounds__(256, 1) void route_f32(
    const float* __restrict__ X, const float* __restrict__ W,
    const float* __restrict__ vsum, float* __restrict__ partial)
{
  const int jt   = blockIdx.x & 63;
  const int bq   = blockIdx.x >> 6;
  const int tid  = threadIdx.x;
  const int wave = tid >> 6;
  const int lane = tid & 63;
  const int c    = lane & 31;
  const int o0   = (lane >> 5) << 4;
  const int b0   = bq * 16 + wave * 4;

  float acc[4][16];
#pragma unroll
  for (int bl = 0; bl < 4; ++bl)
#pragma unroll
    for (int ol = 0; ol < 16; ++ol) acc[bl][ol] = 0.f;

  const float* wbase = W + ((size_t)c * JJ * OO + (size_t)o0) * DI;

  for (int jj = 0; jj < 32; ++jj) {
    const int j = jt * 32 + jj;
    float xf[4][16];
#pragma unroll
    for (int bl = 0; bl < 4; ++bl) {
      const float4* xpt = (const float4*)(X + ((size_t)(b0 + bl) * JJ + j) * DI);
#pragma unroll
      for (int q = 0; q < 4; ++q) {
        float4 x4 = xpt[q];
        xf[bl][4*q+0] = x4.x; xf[bl][4*q+1] = x4.y;
        xf[bl][4*q+2] = x4.z; xf[bl][4*q+3] = x4.w;
      }
    }
    const float4* wp = (const float4*)(wbase + (size_t)j * OO * DI);
    float tv[4][16];
#pragma unroll
    for (int ol = 0; ol < 16; ++ol) {
      float wf[16];
#pragma unroll
      for (int q = 0; q < 4; ++q) {
        float4 w4 = wp[4*ol + q];
        wf[4*q+0] = w4.x; wf[4*q+1] = w4.y;
        wf[4*q+2] = w4.z; wf[4*q+3] = w4.w;
      }
#pragma unroll
      for (int bl = 0; bl < 4; ++bl) {
        float tt = 0.f;
#pragma unroll
        for (int i = 0; i < 16; ++i) tt = fmaf(wf[i], xf[bl][i], tt);
        if (!HAVE_V) acc[bl][ol] += tt;
        else         tv[bl][ol] = tt;
      }
    }
    if (HAVE_V) {
#pragma unroll
      for (int bl = 0; bl < 4; ++bl) {
        float dsum = 0.f;
        const float4* vp = (const float4*)(vsum + (size_t)(b0 + bl) * CO + c * OO + o0);
#pragma unroll
        for (int q = 0; q < 4; ++q) {
          float4 v4 = vp[q];
          dsum = fmaf(v4.x, tv[bl][4*q+0], dsum);
          dsum = fmaf(v4.y, tv[bl][4*q+1], dsum);
          dsum = fmaf(v4.z, tv[bl][4*q+2], dsum);
          dsum = fmaf(v4.w, tv[bl][4*q+3], dsum);
        }
        dsum += __shfl_xor(dsum, 32);
        float mm = dsum;
#pragma unroll
        for (int s = 16; s >= 1; s >>= 1) mm = fmaxf(mm, __shfl_xor(mm, s));
        float e = __expf(dsum - mm);
        float den = e;
#pragma unroll
        for (int s = 16; s >= 1; s >>= 1) den += __shfl_xor(den, s);
        float coef = e / den;
#pragma unroll
        for (int ol = 0; ol < 16; ++ol)
          acc[bl][ol] = fmaf(coef, tv[bl][ol], acc[bl][ol]);
      }
    }
  }
  const float cs = HAVE_V ? 1.f : 0.03125f;
#pragma unroll
  for (int bl = 0; bl < 4; ++bl) {
    float* pp = partial + ((size_t)jt * BB + (b0 + bl)) * CO + c * OO + o0;
#pragma unroll
    for (int q = 0; q < 4; ++q) {
      float4 w4 = make_float4(acc[bl][4*q+0]*cs, acc[bl][4*q+1]*cs,
                              acc[bl][4*q+2]*cs, acc[bl][4*q+3]*cs);
      ((float4*)pp)[q] = w4;
    }
  }
}

// Sum NJT bf16 j-tile partials -> s[b,c,o]; squash over o; vsum / out.
__global__ __launch_bounds__(256, 1) void reduce_squash_bf(
    const ushort_t* __restrict__ partial, float* __restrict__ vsum,
    float* __restrict__ out, int mode)   // 0: vsum = v; 1: vsum += v; 2: out = v
{
  const int idx = blockIdx.x * 256 + threadIdx.x;   // = b*CO + c*OO + o
  float s0 = 0.f, s1 = 0.f, s2 = 0.f, s3 = 0.f;
#pragma unroll 4
  for (int nt = 0; nt < NJT; nt += 4) {
    s0 += bf2f(partial[(size_t)(nt + 0) * (BB * CO) + idx]);
    s1 += bf2f(partial[(size_t)(nt + 1) * (BB * CO) + idx]);
    s2 += bf2f(partial[(size_t)(nt + 2) * (BB * CO) + idx]);
    s3 += bf2f(partial[(size_t)(nt + 3) * (BB * CO) + idx]);
  }
  float s = (s0 + s1) + (s2 + s3);
  float s2m = s * s;
#pragma unroll
  for (int mk = 16; mk >= 1; mk >>= 1) s2m += __shfl_xor(s2m, mk);
  float scale = s2m / ((1.f + s2m) * sqrtf(s2m + 1e-7f));
  float v = scale * s;
  if (mode == 2)      out[idx] = v;
  else if (mode == 1) vsum[idx] += v;
  else                vsum[idx] = v;
}

// f32 reduce for the fallback path
template<int NJTR>
__global__ __launch_bounds__(256, 1) void reduce_squash(
    const float* __restrict__ partial, float* __restrict__ vsum,
    float* __restrict__ out, int mode)
{
  const int idx = blockIdx.x * 256 + threadIdx.x;
  float s0 = 0.f, s1 = 0.f, s2 = 0.f, s3 = 0.f;
#pragma unroll 4
  for (int nt = 0; nt < NJTR; nt += 4) {
    s0 += partial[(size_t)(nt + 0) * (BB * CO) + idx];
    s1 += partial[(size_t)(nt + 1) * (BB * CO) + idx];
    s2 += partial[(size_t)(nt + 2) * (BB * CO) + idx];
    s3 += partial[(size_t)(nt + 3) * (BB * CO) + idx];
  }
  float s = (s0 + s1) + (s2 + s3);
  float s2m = s * s;
#pragma unroll
  for (int mk = 16; mk >= 1; mk >>= 1) s2m += __shfl_xor(s2m, mk);
  float scale = s2m / ((1.f + s2m) * sqrtf(s2m + 1e-7f));
  float v = scale * s;
  if (mode == 2)      out[idx] = v;
  else if (mode == 1) vsum[idx] += v;
  else                vsum[idx] = v;
}

static void run_mfma(const float* X, const float* W, float* out,
                     void* d_ws, hipStream_t stream)
{
  uint2* W2         = (uint2*)d_ws;
  uint2* X3         = (uint2*)((char*)d_ws + W2_BYTES);
  ushort_t* partial = (ushort_t*)((char*)d_ws + W2_BYTES + X3_BYTES);
  float* vsum       = (float*)((char*)d_ws + W2_BYTES + X3_BYTES
                               + (size_t)NJT * BB * CO * 2);
  const int grid  = NJT * 2;         // 256 blocks of 1024
  const int rgrid = BB * CO / 256;

  prep_x<<<2048, 256, 0, stream>>>(X, X3);

  // pass 0 converts W inline and emits W2 for passes 1-2 (prep_w deleted)
  route_conv<<<grid, 1024, 0, stream>>>((const uint4*)X3, W, W2, partial);
  reduce_squash_bf<<<rgrid, 256, 0, stream>>>(partial, vsum, nullptr, 0);

  route_v<<<grid, 1024, 0, stream>>>((const uint4*)X3, (const uint4*)W2, vsum, partial);
  reduce_squash_bf<<<rgrid, 256, 0, stream>>>(partial, vsum, nullptr, 1);

  route_v<<<grid, 1024, 0, stream>>>((const uint4*)X3, (const uint4*)W2, vsum, partial);
  reduce_squash_bf<<<rgrid, 256, 0, stream>>>(partial, vsum, out, 2);
}

static void run_f32_fallback(const float* X, const float* W, float* out,
                             void* d_ws, hipStream_t stream)
{
  float* partial = (float*)d_ws;
  float* vsum    = partial + (size_t)64 * BB * CO;
  const int grid  = 64 * 4;
  const int rgrid = BB * CO / 256;

  route_f32<false><<<grid, 256, 0, stream>>>(X, W, nullptr, partial);
  reduce_squash<64><<<rgrid, 256, 0, stream>>>(partial, vsum, nullptr, 0);
  route_f32<true><<<grid, 256, 0, stream>>>(X, W, vsum, partial);
  reduce_squash<64><<<rgrid, 256, 0, stream>>>(partial, vsum, nullptr, 1);
  route_f32<true><<<grid, 256, 0, stream>>>(X, W, vsum, partial);
  reduce_squash<64><<<rgrid, 256, 0, stream>>>(partial, vsum, out, 2);
}

extern "C" void kernel_launch(void* const* d_in, const int* in_sizes, int n_in,
                              void* d_out, int out_size, void* d_ws, size_t ws_size,
                              hipStream_t stream) {
  (void)in_sizes; (void)n_in; (void)out_size;
  const float* X = (const float*)d_in[0];   // x [64,2048,16] f32
  const float* W = (const float*)d_in[1];   // W [32,2048,32,16] f32
  float* out = (float*)d_out;               // v [64,32,32] f32

  const size_t need = W2_BYTES + X3_BYTES
                    + (size_t)NJT * BB * CO * 2 + (size_t)BB * CO * 4;
  if (ws_size >= need) run_mfma(X, W, out, d_ws, stream);
  else                 run_f32_fallback(X, W, out, d_ws, stream);
}